// Round 2
// baseline (448.085 us; speedup 1.0000x reference)
//
#include <hip/hip_runtime.h>
#include <stdint.h>

#define DIN  512
#define DE   256
#define NC   1024
#define M_   65536
#define FLAGCAP 16384

typedef unsigned short u16;
typedef __attribute__((ext_vector_type(8))) short short8_t;   // 8 bf16
typedef __attribute__((ext_vector_type(4))) float f32x4_t;    // MFMA acc (16x16)
typedef __attribute__((ext_vector_type(16))) float f32x16_t;  // MFMA acc (32x32)

__device__ __forceinline__ float bf2f(u16 u) {
    unsigned x = ((unsigned)u) << 16; return __builtin_bit_cast(float, x);
}
__device__ __forceinline__ u16 f2bf(float f) {
    unsigned x = __builtin_bit_cast(unsigned, f);
    x += 0x7fffu + ((x >> 16) & 1u);
    return (u16)(x >> 16);
}
__device__ __forceinline__ void cvt8_hl(float4 a, float4 b, short8_t& h, short8_t& l) {
    float v[8] = {a.x,a.y,a.z,a.w, b.x,b.y,b.z,b.w};
#pragma unroll
    for (int j = 0; j < 8; ++j) {
        u16 hh = f2bf(v[j]);
        h[j] = (short)hh; l[j] = (short)f2bf(v[j] - bf2f(hh));
    }
}
__device__ __forceinline__ short8_t cvt8(float4 a, float4 b) {
    float v[8] = {a.x,a.y,a.z,a.w, b.x,b.y,b.z,b.w};
    short8_t h;
#pragma unroll
    for (int j = 0; j < 8; ++j) h[j] = (short)f2bf(v[j]);
    return h;
}

// ---------------------------------------------------------------------------
// K0: emb/Wd -> bf16 hi/lo; cnorm (f64); zero lossacc/flagcnt
// ---------------------------------------------------------------------------
__global__ void k_init(const float* __restrict__ emb, const float* __restrict__ Wd,
                       u16* __restrict__ embH, u16* __restrict__ embL,
                       u16* __restrict__ WdH,  u16* __restrict__ WdL,
                       float* __restrict__ cnorm,
                       float* __restrict__ lossacc, int* __restrict__ flagcnt) {
    int tid = blockIdx.x * 256 + threadIdx.x;           // 65536 threads
    for (int i = tid; i < DE * DIN; i += 65536) {
        float v = Wd[i]; u16 h = f2bf(v);
        WdH[i] = h; WdL[i] = f2bf(v - bf2f(h));
    }
    for (int i = tid; i < NC * DE; i += 65536) {
        float v = emb[i]; u16 h = f2bf(v);
        embH[i] = h; embL[i] = f2bf(v - bf2f(h));
    }
    if (tid < NC) {
        const float* c = emb + (size_t)tid * DE;
        double s = 0.0;
        for (int j = 0; j < DE; ++j) { double v = c[j]; s += v * v; }
        cnorm[tid] = (float)s;
    }
    if (tid < 16) lossacc[tid] = 0.f;
    if (tid == 16) *flagcnt = 0;
}

// ---------------------------------------------------------------------------
// K1: fused z_e GEMM + argmin. grid 512 x 256 thr (4 waves) -> 2 blocks/CU,
// one generation. Block owns 128 z-rows. All MFMA 32x32x16, 3-term hi/lo.
//
// Phase 1 (z_e = Z @ Wd^T, full M=256): Wd tile [256m][32K] staged per kt as
// two 128-row halves into aH/aL[0|1] (no dbuf; 2 barriers/kt). T14 split:
// issue kt+1 global loads -> 48 MFMAs on kt -> barrier -> ds_write -> barrier.
// z converted f32->hi/lo in-register, once total per element.
// Epilogue: rownorm in-register (lane + shfl_xor32), f32 stores of out_ze.
//
// Phase 2 (argmin over 1024 codes): round-1 proven body, reordered to T14
// (prefetch loads -> MFMA -> ds_write -> barrier). B-regs reloaded from the
// just-written out_ze rows (same-wave L1 hit).
// ---------------------------------------------------------------------------
__global__ __launch_bounds__(256, 2) void k_fused(
        const float* __restrict__ Z,
        const u16* __restrict__ WdH, const u16* __restrict__ WdL,
        const u16* __restrict__ embH, const u16* __restrict__ embL,
        const float* __restrict__ cnorm,
        float* __restrict__ zeF,
        u16* __restrict__ codew, int* __restrict__ flaglist,
        int* __restrict__ flagcnt, float* __restrict__ lossacc) {
    __shared__ __align__(16) u16 aH[2][128 * 40];
    __shared__ __align__(16) u16 aL[2][128 * 40];
    __shared__ float lCn[NC];
    __shared__ float lLoss[128];
    const int m0 = blockIdx.x * 128;
    const int t = threadIdx.x, lane = t & 63, wv = t >> 6;
    const int lc = lane & 31, hi = lane >> 5;
    const int zrow = m0 + wv * 32 + lc;

    for (int i = t; i < NC; i += 256) lCn[i] = cnorm[i];

    // ===================== Phase 1: z_e =====================
    const int srow = t >> 1, sseg = (t & 1) * 16;   // staging: row, 16-u16 half
    const float* Zrow = Z + (size_t)zrow * DIN;

    uint4 qh[2][2], ql[2][2];
#define WD_LOAD(kt_) { \
    _Pragma("unroll") for (int b = 0; b < 2; ++b) { \
        size_t off = (size_t)(b * 128 + srow) * DIN + (size_t)(kt_) * 32 + sseg; \
        qh[b][0] = *(const uint4*)(WdH + off); qh[b][1] = *(const uint4*)(WdH + off + 8); \
        ql[b][0] = *(const uint4*)(WdL + off); ql[b][1] = *(const uint4*)(WdL + off + 8); } }
#define WD_WRITE() { \
    _Pragma("unroll") for (int b = 0; b < 2; ++b) { \
        *(uint4*)&aH[b][srow * 40 + sseg]     = qh[b][0]; \
        *(uint4*)&aH[b][srow * 40 + sseg + 8] = qh[b][1]; \
        *(uint4*)&aL[b][srow * 40 + sseg]     = ql[b][0]; \
        *(uint4*)&aL[b][srow * 40 + sseg + 8] = ql[b][1]; } }
#define Z_LOAD(kt_, d_) { \
        const float4* zp = (const float4*)(Zrow + (kt_) * 32 + hi * 8); \
        d_[0] = zp[0]; d_[1] = zp[1]; \
        const float4* zq = (const float4*)(Zrow + (kt_) * 32 + 16 + hi * 8); \
        d_[2] = zq[0]; d_[3] = zq[1]; }

    float4 zr[4], zn[4];
    Z_LOAD(0, zr);
    WD_LOAD(0);
    WD_WRITE();
    __syncthreads();

    f32x16_t acc[8];
#pragma unroll
    for (int s = 0; s < 8; ++s)
#pragma unroll
        for (int r = 0; r < 16; ++r) acc[s][r] = 0.f;

    for (int kt = 0; kt < 16; ++kt) {
        if (kt < 15) { WD_LOAD(kt + 1); Z_LOAD(kt + 1, zn); }
        short8_t zh0, zl0, zh1, zl1;
        cvt8_hl(zr[0], zr[1], zh0, zl0);
        cvt8_hl(zr[2], zr[3], zh1, zl1);
#pragma unroll
        for (int ks = 0; ks < 2; ++ks) {
            short8_t zbh = ks ? zh1 : zh0, zbl = ks ? zl1 : zl0;
#pragma unroll
            for (int s = 0; s < 8; ++s) {
                const int lo = ((s & 3) * 32 + lc) * 40 + ks * 16 + hi * 8;
                short8_t ah = *(const short8_t*)&aH[s >> 2][lo];
                short8_t al = *(const short8_t*)&aL[s >> 2][lo];
                acc[s] = __builtin_amdgcn_mfma_f32_32x32x16_bf16(ah, zbh, acc[s], 0, 0, 0);
                acc[s] = __builtin_amdgcn_mfma_f32_32x32x16_bf16(ah, zbl, acc[s], 0, 0, 0);
                acc[s] = __builtin_amdgcn_mfma_f32_32x32x16_bf16(al, zbh, acc[s], 0, 0, 0);
            }
        }
        if (kt < 15) {
            __syncthreads();
            WD_WRITE();
            zr[0] = zn[0]; zr[1] = zn[1]; zr[2] = zn[2]; zr[3] = zn[3];
            __syncthreads();
        }
    }
#undef WD_LOAD
#undef WD_WRITE
#undef Z_LOAD

    // epilogue: rownorm + z_e store. acc[s][r] -> m = s*32 + (r&3)+8*(r>>2)+4*hi
    float rn = 0.f;
#pragma unroll
    for (int s = 0; s < 8; ++s)
#pragma unroll
        for (int r = 0; r < 16; ++r) rn += acc[s][r] * acc[s][r];
    rn += __shfl_xor(rn, 32, 64);
#pragma unroll
    for (int s = 0; s < 8; ++s)
#pragma unroll
        for (int q = 0; q < 4; ++q) {
            float4 v = {acc[s][q * 4 + 0], acc[s][q * 4 + 1],
                        acc[s][q * 4 + 2], acc[s][q * 4 + 3]};
            *(float4*)(zeF + (size_t)zrow * DE + s * 32 + q * 8 + hi * 4) = v;
        }
    __syncthreads();   // drains vmcnt: own-wave stores visible for reload

    // ===================== Phase 2: argmin =====================
    short8_t bh[16], bl[16];
#pragma unroll
    for (int c = 0; c < 16; ++c) {
        const float4* zp = (const float4*)(zeF + (size_t)zrow * DE + c * 16 + hi * 8);
        cvt8_hl(zp[0], zp[1], bh[c], bl[c]);
    }

    uint4 ph[2], pl[2];
#define STAGE_LOAD(ct_, kt_) { \
    _Pragma("unroll") for (int j = 0; j < 2; ++j) { \
        int idx = t + j * 256; int row = idx >> 2, seg = (idx & 3) * 8; \
        size_t off = (size_t)((ct_) * 128 + row) * DE + (size_t)(kt_) * 32 + seg; \
        ph[j] = *(const uint4*)(embH + off); \
        pl[j] = *(const uint4*)(embL + off); } }
#define STAGE_WRITE(b_) { \
    _Pragma("unroll") for (int j = 0; j < 2; ++j) { \
        int idx = t + j * 256; int row = idx >> 2, seg = (idx & 3) * 8; \
        *(uint4*)&aH[b_][row * 40 + seg] = ph[j]; \
        *(uint4*)&aL[b_][row * 40 + seg] = pl[j]; } }

    float best = 3.4e38f, sec = 3.4e38f; int bidx = 0;
    STAGE_LOAD(0, 0); STAGE_WRITE(0);
    for (int ct = 0; ct < 8; ++ct) {
        f32x16_t ac2[4];
#pragma unroll
        for (int s = 0; s < 4; ++s)
#pragma unroll
            for (int r = 0; r < 16; ++r) ac2[s][r] = 0.f;
#pragma unroll
        for (int kt = 0; kt < 8; ++kt) {
            __syncthreads();
            const bool pf = (kt < 7) || (ct < 7);
            if (kt < 7)      { STAGE_LOAD(ct, kt + 1) }
            else if (ct < 7) { STAGE_LOAD(ct + 1, 0) }
            const int buf = kt & 1;
#pragma unroll
            for (int ks = 0; ks < 2; ++ks) {
                const int c = kt * 2 + ks;
#pragma unroll
                for (int s = 0; s < 4; ++s) {
                    const int lo = (s * 32 + lc) * 40 + ks * 16 + hi * 8;
                    short8_t ah = *(const short8_t*)&aH[buf][lo];
                    short8_t al = *(const short8_t*)&aL[buf][lo];
                    ac2[s] = __builtin_amdgcn_mfma_f32_32x32x16_bf16(ah, bh[c], ac2[s], 0, 0, 0);
                    ac2[s] = __builtin_amdgcn_mfma_f32_32x32x16_bf16(ah, bl[c], ac2[s], 0, 0, 0);
                    ac2[s] = __builtin_amdgcn_mfma_f32_32x32x16_bf16(al, bh[c], ac2[s], 0, 0, 0);
                }
            }
            if (pf) { STAGE_WRITE((kt + 1) & 1) }
        }
        // fold chunk into best/sec
#pragma unroll
        for (int s = 0; s < 4; ++s)
#pragma unroll
            for (int r = 0; r < 16; ++r) {
                const int cidx = ct * 128 + s * 32 + (r & 3) + 8 * (r >> 2) + 4 * hi;
                float d = fmaf(-2.f, ac2[s][r], lCn[cidx]);
                bool lt = d < best;
                sec  = lt ? best : fminf(sec, d);
                best = lt ? d : best;
                bidx = lt ? cidx : bidx;
            }
    }
#undef STAGE_LOAD
#undef STAGE_WRITE
    // merge lane pair (l, l^32)
    {
        float ob = __shfl_xor(best, 32, 64);
        float os = __shfl_xor(sec,  32, 64);
        int   oi = __shfl_xor(bidx, 32, 64);
        float ns = fminf(fminf(sec, os), fmaxf(best, ob));
        if (ob < best) { best = ob; bidx = oi; }
        sec = ns;
    }
    if (lane < 32) {
        codew[zrow] = (u16)bidx;
        if (sec - best < 0.02f) {
            int pos = atomicAdd(flagcnt, 1);
            if (pos < FLAGCAP) flaglist[pos] = zrow;
        }
        lLoss[wv * 32 + lc] = rn + best;
    }
    __syncthreads();
    for (int str = 64; str > 0; str >>= 1) {
        if (t < str) lLoss[t] += lLoss[t + str];
        __syncthreads();
    }
    if (t == 0) atomicAdd(&lossacc[m0 >> 12], lLoss[0]);
}

// ---------------------------------------------------------------------------
// K2b: f64 exact re-argmin for flagged rows, from pristine f32 inputs.
// ---------------------------------------------------------------------------
__global__ __launch_bounds__(256) void k_refine(
        const float* __restrict__ Z, const float* __restrict__ Wd,
        const float* __restrict__ emb,
        const int* __restrict__ flaglist, const int* __restrict__ flagcnt,
        u16* __restrict__ codew) {
    __shared__ float  lz[DIN];
    __shared__ double lze[DE];
    __shared__ double ld[256];
    __shared__ int    li[256];
    int n = *flagcnt; if (n < 0) n = 0; if (n > FLAGCAP) n = FLAGCAP;
    int t = threadIdx.x;
    for (int f = blockIdx.x; f < n; f += gridDim.x) {
        int row = flaglist[f] & (M_ - 1);
        __syncthreads();
        for (int i = t; i < DIN; i += 256) lz[i] = Z[(size_t)row * DIN + i];
        __syncthreads();
        double a = 0.0;
        const float* wr = Wd + (size_t)t * DIN;
        for (int k = 0; k < DIN; ++k) a += (double)lz[k] * (double)wr[k];
        lze[t] = a;
        __syncthreads();
        double bd = 1e300; int bi = 0;
        for (int cc = 0; cc < 4; ++cc) {
            int c = cc * 256 + t;
            const float* cr = emb + (size_t)c * DE;
            double s = 0.0;
            for (int e = 0; e < DE; ++e) {
                double diff = lze[e] - (double)cr[e];
                s += diff * diff;
            }
            if (s < bd) { bd = s; bi = c; }
        }
        ld[t] = bd; li[t] = bi;
        __syncthreads();
        for (int str = 128; str > 0; str >>= 1) {
            if (t < str) {
                double od = ld[t + str]; int oi = li[t + str];
                if (od < ld[t] || (od == ld[t] && oi < li[t])) { ld[t] = od; li[t] = oi; }
            }
            __syncthreads();
        }
        if (t == 0) codew[row] = (u16)li[0];
        __syncthreads();
    }
}

// ---------------------------------------------------------------------------
__global__ void k_loss(const float* __restrict__ lossacc,
                       float* __restrict__ out_commit, float* __restrict__ out_codebook) {
    int tid = threadIdx.x;
    if (tid < 16) {
        float v = lossacc[tid] * (1.f / 1048576.f);
        out_commit[tid] = v; out_codebook[tid] = v;
    }
}
__global__ void k_codef(const u16* __restrict__ codew, float* __restrict__ out_code) {
    int tid = blockIdx.x * 256 + threadIdx.x;
    if (tid < M_) out_code[tid] = (float)(codew[tid] & (NC - 1));
}

// ---------------------------------------------------------------------------
// K3: z_q_out = emb[code] @ Wu^T, single bf16 term.
// ---------------------------------------------------------------------------
__global__ __launch_bounds__(512) void k_gemm3(
        const float* __restrict__ emb, const float* __restrict__ Wu,
        const float* __restrict__ out_code, float* __restrict__ out) {
    __shared__ __align__(16) u16 gA[128 * 264];   // 67.6 KB
    const int bz = blockIdx.x >> 1, nh = blockIdx.x & 1;
    const int m0 = bz * 128;
    const int t = threadIdx.x, lane = t & 63, wv = t >> 6;
    const int lr = lane & 15, lg = lane >> 4;
    {
        const int row = t >> 2, seg = (t & 3) * 64;
        const int code = (int)out_code[m0 + row] & (NC - 1);
        const float* src = emb + (size_t)code * DE + seg;
#pragma unroll
        for (int j = 0; j < 8; ++j) {
            const float4* p = (const float4*)(src + j * 8);
            *(short8_t*)&gA[row * 264 + seg + j * 8] = cvt8(p[0], p[1]);
        }
    }
    __syncthreads();

    const int nbase = nh * 256 + wv * 32;
    f32x4_t acc[8][2];
#pragma unroll
    for (int i = 0; i < 8; ++i)
#pragma unroll
        for (int j = 0; j < 2; ++j) acc[i][j] = (f32x4_t){0.f, 0.f, 0.f, 0.f};

#pragma unroll
    for (int kt = 0; kt < 8; ++kt) {
        const int k0 = kt * 32 + lg * 8;
        short8_t b0, b1;
        {
            const float4* p = (const float4*)(Wu + (size_t)(nbase + lr) * DE + k0);
            b0 = cvt8(p[0], p[1]);
            const float4* q = (const float4*)(Wu + (size_t)(nbase + 16 + lr) * DE + k0);
            b1 = cvt8(q[0], q[1]);
        }
#pragma unroll
        for (int mi = 0; mi < 8; ++mi) {
            short8_t a = *(const short8_t*)&gA[(mi * 16 + lr) * 264 + k0];
            acc[mi][0] = __builtin_amdgcn_mfma_f32_16x16x32_bf16(a, b0, acc[mi][0], 0, 0, 0);
            acc[mi][1] = __builtin_amdgcn_mfma_f32_16x16x32_bf16(a, b1, acc[mi][1], 0, 0, 0);
        }
    }
#pragma unroll
    for (int mi = 0; mi < 8; ++mi)
#pragma unroll
        for (int reg = 0; reg < 4; ++reg) {
            const int zr = m0 + mi * 16 + lg * 4 + reg;
            out[(size_t)zr * DIN + nbase + lr]      = acc[mi][0][reg];
            out[(size_t)zr * DIN + nbase + 16 + lr] = acc[mi][1][reg];
        }
}

// ---------------------------------------------------------------------------
extern "C" void kernel_launch(void* const* d_in, const int* in_sizes, int n_in,
                              void* d_out, int out_size, void* d_ws, size_t ws_size,
                              hipStream_t stream) {
    const float* Z   = (const float*)d_in[0];   // [16,4096,512] f32
    const float* E   = (const float*)d_in[1];   // [1024,256]    f32
    const float* Wd  = (const float*)d_in[2];   // [256,512]     f32
    const float* Wu  = (const float*)d_in[3];   // [512,256]     f32

    float* out       = (float*)d_out;           // f32 outputs, concat
    float* out_zq    = out;                     // [0, 33554432)
    float* out_com   = out + 33554432;          // 16
    float* out_cb    = out + 33554448;          // 16
    float* out_code  = out + 33554464;          // 65536
    float* out_ze    = out + 33620000;          // 16,777,216

    char* scr = (char*)d_out;
    u16*   embH     = (u16*)  (scr + 0);          // 524,288 B
    u16*   embL     = (u16*)  (scr + 524288);     // 524,288 B
    u16*   WdH      = (u16*)  (scr + 1048576);    // 262,144 B
    u16*   WdL      = (u16*)  (scr + 1310720);    // 262,144 B
    float* cnorm    = (float*)(scr + 1572864);    //   4,096 B
    u16*   codew    = (u16*)  (scr + 1839104);    // 131,072 B
    int*   flaglist = (int*)  (scr + 1970176);    //  65,536 B
    int*   flagcnt  = (int*)  (scr + 2035712);    //      64 B
    float* lossacc  = (float*)(scr + 2035776);    //      64 B
    (void)d_ws; (void)ws_size; (void)in_sizes; (void)n_in; (void)out_size;

    k_init  <<<256, 256, 0, stream>>>(E, Wd, embH, embL, WdH, WdL, cnorm,
                                      lossacc, flagcnt);
    k_fused <<<512, 256, 0, stream>>>(Z, WdH, WdL, embH, embL, cnorm, out_ze,
                                      codew, flaglist, flagcnt, lossacc);
    k_refine<<<128, 256, 0, stream>>>(Z, Wd, E, flaglist, flagcnt, codew);
    k_loss  <<<1,   64,  0, stream>>>(lossacc, out_com, out_cb);
    k_codef <<<256, 256, 0, stream>>>(codew, out_code);
    k_gemm3 <<<1024,512, 0, stream>>>(E, Wu, out_code, out_zq);
}

// Round 3
// 424.375 us; speedup vs baseline: 1.0559x; 1.0559x over previous
//
#include <hip/hip_runtime.h>
#include <stdint.h>

#define DIN  512
#define DE   256
#define NC   1024
#define M_   65536
#define FLAGCAP 16384

typedef unsigned short u16;
typedef __attribute__((ext_vector_type(8))) short short8_t;   // 8 bf16
typedef __attribute__((ext_vector_type(4))) float f32x4_t;    // MFMA acc (16x16)
typedef __attribute__((ext_vector_type(16))) float f32x16_t;  // MFMA acc (32x32)

__device__ __forceinline__ float bf2f(u16 u) {
    unsigned x = ((unsigned)u) << 16; return __builtin_bit_cast(float, x);
}
__device__ __forceinline__ u16 f2bf(float f) {
    unsigned x = __builtin_bit_cast(unsigned, f);
    x += 0x7fffu + ((x >> 16) & 1u);
    return (u16)(x >> 16);
}
__device__ __forceinline__ void cvt8_hl(float4 a, float4 b, short8_t& h, short8_t& l) {
    float v[8] = {a.x,a.y,a.z,a.w, b.x,b.y,b.z,b.w};
#pragma unroll
    for (int j = 0; j < 8; ++j) {
        u16 hh = f2bf(v[j]);
        h[j] = (short)hh; l[j] = (short)f2bf(v[j] - bf2f(hh));
    }
}
__device__ __forceinline__ short8_t cvt8(float4 a, float4 b) {
    float v[8] = {a.x,a.y,a.z,a.w, b.x,b.y,b.z,b.w};
    short8_t h;
#pragma unroll
    for (int j = 0; j < 8; ++j) h[j] = (short)f2bf(v[j]);
    return h;
}

// ---------------------------------------------------------------------------
// K0: emb/Wd -> bf16 hi/lo; cnorm (f64); zero lossacc/flagcnt
// ---------------------------------------------------------------------------
__global__ void k_init(const float* __restrict__ emb, const float* __restrict__ Wd,
                       u16* __restrict__ embH, u16* __restrict__ embL,
                       u16* __restrict__ WdH,  u16* __restrict__ WdL,
                       float* __restrict__ cnorm,
                       float* __restrict__ lossacc, int* __restrict__ flagcnt) {
    int tid = blockIdx.x * 256 + threadIdx.x;           // 65536 threads
    for (int i = tid; i < DE * DIN; i += 65536) {
        float v = Wd[i]; u16 h = f2bf(v);
        WdH[i] = h; WdL[i] = f2bf(v - bf2f(h));
    }
    for (int i = tid; i < NC * DE; i += 65536) {
        float v = emb[i]; u16 h = f2bf(v);
        embH[i] = h; embL[i] = f2bf(v - bf2f(h));
    }
    if (tid < NC) {
        const float* c = emb + (size_t)tid * DE;
        double s = 0.0;
        for (int j = 0; j < DE; ++j) { double v = c[j]; s += v * v; }
        cnorm[tid] = (float)s;
    }
    if (tid < 16) lossacc[tid] = 0.f;
    if (tid == 16) *flagcnt = 0;
}

// ---------------------------------------------------------------------------
// K1: z_e = Z @ Wd^T, 32x32x16 MFMA, 3-term hi/lo. grid 512 x 256 thr
// (4 waves) -> exactly 2 blocks/CU. Block owns 128 z-rows, computes all
// M=256 outputs. Wd tile [256m][32K] staged per kt as two 128-row halves
// into aH/aL[0|1]. T14 split: issue kt+1 global loads -> 48 MFMA/wave on kt
// -> barrier -> ds_write -> barrier. z converted hi/lo in-register once.
// rownorm computed in-register, stored directly (no atomics).
// Register budget: acc 128 (AGPR) + z 32 + staging 32 + temps ~ 220 <= 256.
// ---------------------------------------------------------------------------
__global__ __launch_bounds__(256, 2) void k_ze(
        const float* __restrict__ Z,
        const u16* __restrict__ WdH, const u16* __restrict__ WdL,
        float* __restrict__ zeF, float* __restrict__ rownorm) {
    __shared__ __align__(16) u16 aH[2][128 * 40];
    __shared__ __align__(16) u16 aL[2][128 * 40];
    const int m0 = blockIdx.x * 128;
    const int t = threadIdx.x, lane = t & 63, wv = t >> 6;
    const int lc = lane & 31, hi = lane >> 5;
    const int zrow = m0 + wv * 32 + lc;
    const int srow = t >> 1, sseg = (t & 1) * 16;   // staging: row, 16-u16 half
    const float* Zrow = Z + (size_t)zrow * DIN;

    uint4 qh[2][2], ql[2][2];
#define WD_LOAD(kt_) { \
    _Pragma("unroll") for (int b = 0; b < 2; ++b) { \
        size_t off = (size_t)(b * 128 + srow) * DIN + (size_t)(kt_) * 32 + sseg; \
        qh[b][0] = *(const uint4*)(WdH + off); qh[b][1] = *(const uint4*)(WdH + off + 8); \
        ql[b][0] = *(const uint4*)(WdL + off); ql[b][1] = *(const uint4*)(WdL + off + 8); } }
#define WD_WRITE() { \
    _Pragma("unroll") for (int b = 0; b < 2; ++b) { \
        *(uint4*)&aH[b][srow * 40 + sseg]     = qh[b][0]; \
        *(uint4*)&aH[b][srow * 40 + sseg + 8] = qh[b][1]; \
        *(uint4*)&aL[b][srow * 40 + sseg]     = ql[b][0]; \
        *(uint4*)&aL[b][srow * 40 + sseg + 8] = ql[b][1]; } }
#define Z_LOAD(kt_, d_) { \
        const float4* zp = (const float4*)(Zrow + (kt_) * 32 + hi * 8); \
        d_[0] = zp[0]; d_[1] = zp[1]; \
        const float4* zq = (const float4*)(Zrow + (kt_) * 32 + 16 + hi * 8); \
        d_[2] = zq[0]; d_[3] = zq[1]; }

    float4 zr[4], zn[4];
    Z_LOAD(0, zr);
    WD_LOAD(0);
    WD_WRITE();
    __syncthreads();

    f32x16_t acc[8];
#pragma unroll
    for (int s = 0; s < 8; ++s)
#pragma unroll
        for (int r = 0; r < 16; ++r) acc[s][r] = 0.f;

    for (int kt = 0; kt < 16; ++kt) {
        if (kt < 15) { WD_LOAD(kt + 1); Z_LOAD(kt + 1, zn); }
        short8_t zh0, zl0, zh1, zl1;
        cvt8_hl(zr[0], zr[1], zh0, zl0);
        cvt8_hl(zr[2], zr[3], zh1, zl1);
#pragma unroll
        for (int ks = 0; ks < 2; ++ks) {
            short8_t zbh = ks ? zh1 : zh0, zbl = ks ? zl1 : zl0;
#pragma unroll
            for (int s = 0; s < 8; ++s) {
                const int lo = ((s & 3) * 32 + lc) * 40 + ks * 16 + hi * 8;
                short8_t ah = *(const short8_t*)&aH[s >> 2][lo];
                short8_t al = *(const short8_t*)&aL[s >> 2][lo];
                acc[s] = __builtin_amdgcn_mfma_f32_32x32x16_bf16(ah, zbh, acc[s], 0, 0, 0);
                acc[s] = __builtin_amdgcn_mfma_f32_32x32x16_bf16(ah, zbl, acc[s], 0, 0, 0);
                acc[s] = __builtin_amdgcn_mfma_f32_32x32x16_bf16(al, zbh, acc[s], 0, 0, 0);
            }
        }
        if (kt < 15) {
            __syncthreads();
            WD_WRITE();
            zr[0] = zn[0]; zr[1] = zn[1]; zr[2] = zn[2]; zr[3] = zn[3];
            __syncthreads();
        }
    }
#undef WD_LOAD
#undef WD_WRITE
#undef Z_LOAD

    // epilogue: rownorm + z_e store. acc[s][r] -> m = s*32 + (r&3)+8*(r>>2)+4*hi
    float rn = 0.f;
#pragma unroll
    for (int s = 0; s < 8; ++s)
#pragma unroll
        for (int r = 0; r < 16; ++r) rn += acc[s][r] * acc[s][r];
    rn += __shfl_xor(rn, 32, 64);
    if (lane < 32) rownorm[zrow] = rn;
#pragma unroll
    for (int s = 0; s < 8; ++s)
#pragma unroll
        for (int q = 0; q < 4; ++q) {
            float4 v = {acc[s][q * 4 + 0], acc[s][q * 4 + 1],
                        acc[s][q * 4 + 2], acc[s][q * 4 + 3]};
            *(float4*)(zeF + (size_t)zrow * DE + s * 32 + q * 8 + hi * 4) = v;
        }
}

// ---------------------------------------------------------------------------
// K2: argmin, 32x32x16 MFMA (3-term hi/lo). grid 512 x 256 thr (4 waves).
// (round-1 proven version, unchanged)
// ---------------------------------------------------------------------------
__global__ __launch_bounds__(256, 2) void k_argmin(
        const float* __restrict__ zeF,
        const u16* __restrict__ embH, const u16* __restrict__ embL,
        const float* __restrict__ cnorm, const float* __restrict__ rownorm,
        u16* __restrict__ codew, int* __restrict__ flaglist,
        int* __restrict__ flagcnt, float* __restrict__ lossacc) {
    __shared__ __align__(16) u16 aH[2][128 * 40];
    __shared__ __align__(16) u16 aL[2][128 * 40];
    __shared__ float lCn[NC];
    __shared__ float lLoss[128];
    const int m0 = blockIdx.x * 128;
    const int t = threadIdx.x, lane = t & 63, wv = t >> 6;
    const int lc = lane & 31, hi = lane >> 5;
    const int zrow = m0 + wv * 32 + lc;

    for (int i = t; i < NC; i += 256) lCn[i] = cnorm[i];

    // B-regs: this lane's z row, all K=256 in 16 chunks of 16, hi/lo
    short8_t bh[16], bl[16];
#pragma unroll
    for (int c = 0; c < 16; ++c) {
        const float4* zp = (const float4*)(zeF + (size_t)zrow * DE + c * 16 + hi * 8);
        cvt8_hl(zp[0], zp[1], bh[c], bl[c]);
    }

#define STAGE_E(ct_, kt_, b_) { \
        _Pragma("unroll") \
        for (int j = 0; j < 2; ++j) { \
            int idx = t + j * 256; \
            int row = idx >> 2, seg = (idx & 3) * 8; \
            size_t off = (size_t)((ct_) * 128 + row) * DE + (kt_) * 32 + seg; \
            uint4 vh = *(const uint4*)(embH + off); \
            uint4 vl = *(const uint4*)(embL + off); \
            *(uint4*)&aH[b_][row * 40 + seg] = vh; \
            *(uint4*)&aL[b_][row * 40 + seg] = vl; \
        } }

    float best = 3.4e38f, sec = 3.4e38f; int bidx = 0;
    STAGE_E(0, 0, 0);
    for (int ct = 0; ct < 8; ++ct) {
        f32x16_t acc[4];
#pragma unroll
        for (int s = 0; s < 4; ++s)
#pragma unroll
            for (int r = 0; r < 16; ++r) acc[s][r] = 0.f;
#pragma unroll
        for (int kt = 0; kt < 8; ++kt) {
            __syncthreads();
            if (kt < 7)      STAGE_E(ct, kt + 1, (kt + 1) & 1)
            else if (ct < 7) STAGE_E(ct + 1, 0, 0)
            const int buf = kt & 1;
#pragma unroll
            for (int ks = 0; ks < 2; ++ks) {
                const int c = kt * 2 + ks;
#pragma unroll
                for (int s = 0; s < 4; ++s) {
                    short8_t ah = *(const short8_t*)&aH[buf][(s * 32 + lc) * 40 + ks * 16 + hi * 8];
                    short8_t al = *(const short8_t*)&aL[buf][(s * 32 + lc) * 40 + ks * 16 + hi * 8];
                    acc[s] = __builtin_amdgcn_mfma_f32_32x32x16_bf16(ah, bh[c], acc[s], 0, 0, 0);
                    acc[s] = __builtin_amdgcn_mfma_f32_32x32x16_bf16(ah, bl[c], acc[s], 0, 0, 0);
                    acc[s] = __builtin_amdgcn_mfma_f32_32x32x16_bf16(al, bh[c], acc[s], 0, 0, 0);
                }
            }
        }
        // fold chunk into best/sec
#pragma unroll
        for (int s = 0; s < 4; ++s)
#pragma unroll
            for (int r = 0; r < 16; ++r) {
                const int cidx = ct * 128 + s * 32 + (r & 3) + 8 * (r >> 2) + 4 * hi;
                float d = fmaf(-2.f, acc[s][r], lCn[cidx]);
                bool lt = d < best;
                sec  = lt ? best : fminf(sec, d);
                best = lt ? d : best;
                bidx = lt ? cidx : bidx;
            }
    }
#undef STAGE_E
    // merge lane pair (l, l^32): both halves of the same z-column
    {
        float ob = __shfl_xor(best, 32, 64);
        float os = __shfl_xor(sec,  32, 64);
        int   oi = __shfl_xor(bidx, 32, 64);
        float ns = fminf(fminf(sec, os), fmaxf(best, ob));
        if (ob < best) { best = ob; bidx = oi; }
        sec = ns;
    }
    if (lane < 32) {
        codew[zrow] = (u16)bidx;
        if (sec - best < 0.02f) {
            int pos = atomicAdd(flagcnt, 1);
            if (pos < FLAGCAP) flaglist[pos] = zrow;
        }
        lLoss[wv * 32 + lc] = rownorm[zrow] + best;
    }
    __syncthreads();
    for (int str = 64; str > 0; str >>= 1) {
        if (t < str) lLoss[t] += lLoss[t + str];
        __syncthreads();
    }
    if (t == 0) atomicAdd(&lossacc[m0 >> 12], lLoss[0]);
}

// ---------------------------------------------------------------------------
// K2b: f64 exact re-argmin for flagged rows, from pristine f32 inputs.
// ---------------------------------------------------------------------------
__global__ __launch_bounds__(256) void k_refine(
        const float* __restrict__ Z, const float* __restrict__ Wd,
        const float* __restrict__ emb,
        const int* __restrict__ flaglist, const int* __restrict__ flagcnt,
        u16* __restrict__ codew) {
    __shared__ float  lz[DIN];
    __shared__ double lze[DE];
    __shared__ double ld[256];
    __shared__ int    li[256];
    int n = *flagcnt; if (n < 0) n = 0; if (n > FLAGCAP) n = FLAGCAP;
    int t = threadIdx.x;
    for (int f = blockIdx.x; f < n; f += gridDim.x) {
        int row = flaglist[f] & (M_ - 1);
        __syncthreads();
        for (int i = t; i < DIN; i += 256) lz[i] = Z[(size_t)row * DIN + i];
        __syncthreads();
        double a = 0.0;
        const float* wr = Wd + (size_t)t * DIN;
        for (int k = 0; k < DIN; ++k) a += (double)lz[k] * (double)wr[k];
        lze[t] = a;
        __syncthreads();
        double bd = 1e300; int bi = 0;
        for (int cc = 0; cc < 4; ++cc) {
            int c = cc * 256 + t;
            const float* cr = emb + (size_t)c * DE;
            double s = 0.0;
            for (int e = 0; e < DE; ++e) {
                double diff = lze[e] - (double)cr[e];
                s += diff * diff;
            }
            if (s < bd) { bd = s; bi = c; }
        }
        ld[t] = bd; li[t] = bi;
        __syncthreads();
        for (int str = 128; str > 0; str >>= 1) {
            if (t < str) {
                double od = ld[t + str]; int oi = li[t + str];
                if (od < ld[t] || (od == ld[t] && oi < li[t])) { ld[t] = od; li[t] = oi; }
            }
            __syncthreads();
        }
        if (t == 0) codew[row] = (u16)li[0];
        __syncthreads();
    }
}

// ---------------------------------------------------------------------------
__global__ void k_loss(const float* __restrict__ lossacc,
                       float* __restrict__ out_commit, float* __restrict__ out_codebook) {
    int tid = threadIdx.x;
    if (tid < 16) {
        float v = lossacc[tid] * (1.f / 1048576.f);
        out_commit[tid] = v; out_codebook[tid] = v;
    }
}
__global__ void k_codef(const u16* __restrict__ codew, float* __restrict__ out_code) {
    int tid = blockIdx.x * 256 + threadIdx.x;
    if (tid < M_) out_code[tid] = (float)(codew[tid] & (NC - 1));
}

// ---------------------------------------------------------------------------
// K3: z_q_out = emb[code] @ Wu^T, single bf16 term.
// ---------------------------------------------------------------------------
__global__ __launch_bounds__(512) void k_gemm3(
        const float* __restrict__ emb, const float* __restrict__ Wu,
        const float* __restrict__ out_code, float* __restrict__ out) {
    __shared__ __align__(16) u16 gA[128 * 264];   // 67.6 KB
    const int bz = blockIdx.x >> 1, nh = blockIdx.x & 1;
    const int m0 = bz * 128;
    const int t = threadIdx.x, lane = t & 63, wv = t >> 6;
    const int lr = lane & 15, lg = lane >> 4;
    {
        const int row = t >> 2, seg = (t & 3) * 64;
        const int code = (int)out_code[m0 + row] & (NC - 1);
        const float* src = emb + (size_t)code * DE + seg;
#pragma unroll
        for (int j = 0; j < 8; ++j) {
            const float4* p = (const float4*)(src + j * 8);
            *(short8_t*)&gA[row * 264 + seg + j * 8] = cvt8(p[0], p[1]);
        }
    }
    __syncthreads();

    const int nbase = nh * 256 + wv * 32;
    f32x4_t acc[8][2];
#pragma unroll
    for (int i = 0; i < 8; ++i)
#pragma unroll
        for (int j = 0; j < 2; ++j) acc[i][j] = (f32x4_t){0.f, 0.f, 0.f, 0.f};

#pragma unroll
    for (int kt = 0; kt < 8; ++kt) {
        const int k0 = kt * 32 + lg * 8;
        short8_t b0, b1;
        {
            const float4* p = (const float4*)(Wu + (size_t)(nbase + lr) * DE + k0);
            b0 = cvt8(p[0], p[1]);
            const float4* q = (const float4*)(Wu + (size_t)(nbase + 16 + lr) * DE + k0);
            b1 = cvt8(q[0], q[1]);
        }
#pragma unroll
        for (int mi = 0; mi < 8; ++mi) {
            short8_t a = *(const short8_t*)&gA[(mi * 16 + lr) * 264 + k0];
            acc[mi][0] = __builtin_amdgcn_mfma_f32_16x16x32_bf16(a, b0, acc[mi][0], 0, 0, 0);
            acc[mi][1] = __builtin_amdgcn_mfma_f32_16x16x32_bf16(a, b1, acc[mi][1], 0, 0, 0);
        }
    }
#pragma unroll
    for (int mi = 0; mi < 8; ++mi)
#pragma unroll
        for (int reg = 0; reg < 4; ++reg) {
            const int zr = m0 + mi * 16 + lg * 4 + reg;
            out[(size_t)zr * DIN + nbase + lr]      = acc[mi][0][reg];
            out[(size_t)zr * DIN + nbase + 16 + lr] = acc[mi][1][reg];
        }
}

// ---------------------------------------------------------------------------
extern "C" void kernel_launch(void* const* d_in, const int* in_sizes, int n_in,
                              void* d_out, int out_size, void* d_ws, size_t ws_size,
                              hipStream_t stream) {
    const float* Z   = (const float*)d_in[0];   // [16,4096,512] f32
    const float* E   = (const float*)d_in[1];   // [1024,256]    f32
    const float* Wd  = (const float*)d_in[2];   // [256,512]     f32
    const float* Wu  = (const float*)d_in[3];   // [512,256]     f32

    float* out       = (float*)d_out;           // f32 outputs, concat
    float* out_zq    = out;                     // [0, 33554432)
    float* out_com   = out + 33554432;          // 16
    float* out_cb    = out + 33554448;          // 16
    float* out_code  = out + 33554464;          // 65536
    float* out_ze    = out + 33620000;          // 16,777,216

    char* scr = (char*)d_out;
    u16*   embH     = (u16*)  (scr + 0);          // 524,288 B
    u16*   embL     = (u16*)  (scr + 524288);     // 524,288 B
    u16*   WdH      = (u16*)  (scr + 1048576);    // 262,144 B
    u16*   WdL      = (u16*)  (scr + 1310720);    // 262,144 B
    float* cnorm    = (float*)(scr + 1572864);    //   4,096 B
    float* rownorm  = (float*)(scr + 1576960);    // 262,144 B
    u16*   codew    = (u16*)  (scr + 1839104);    // 131,072 B
    int*   flaglist = (int*)  (scr + 1970176);    //  65,536 B
    int*   flagcnt  = (int*)  (scr + 2035712);    //      64 B
    float* lossacc  = (float*)(scr + 2035776);    //      64 B
    (void)d_ws; (void)ws_size; (void)in_sizes; (void)n_in; (void)out_size;

    k_init  <<<256, 256, 0, stream>>>(E, Wd, embH, embL, WdH, WdL, cnorm,
                                      lossacc, flagcnt);
    k_ze    <<<512, 256, 0, stream>>>(Z, WdH, WdL, out_ze, rownorm);
    k_argmin<<<512, 256, 0, stream>>>(out_ze, embH, embL, cnorm, rownorm,
                                      codew, flaglist, flagcnt, lossacc);
    k_refine<<<128, 256, 0, stream>>>(Z, Wd, E, flaglist, flagcnt, codew);
    k_loss  <<<1,   64,  0, stream>>>(lossacc, out_com, out_cb);
    k_codef <<<256, 256, 0, stream>>>(codew, out_code);
    k_gemm3 <<<1024,512, 0, stream>>>(E, Wu, out_code, out_zq);
}

// Round 4
// 413.639 us; speedup vs baseline: 1.0833x; 1.0260x over previous
//
#include <hip/hip_runtime.h>
#include <stdint.h>

#define DIN  512
#define DE   256
#define NC   1024
#define M_   65536
#define FLAGCAP 16384

typedef unsigned short u16;
typedef __attribute__((ext_vector_type(8))) short short8_t;   // 8 bf16
typedef __attribute__((ext_vector_type(4))) float f32x4_t;    // MFMA acc (16x16)
typedef __attribute__((ext_vector_type(16))) float f32x16_t;  // MFMA acc (32x32)

__device__ __forceinline__ float bf2f(u16 u) {
    unsigned x = ((unsigned)u) << 16; return __builtin_bit_cast(float, x);
}
__device__ __forceinline__ u16 f2bf(float f) {
    unsigned x = __builtin_bit_cast(unsigned, f);
    x += 0x7fffu + ((x >> 16) & 1u);
    return (u16)(x >> 16);
}
__device__ __forceinline__ void cvt8_hl(float4 a, float4 b, short8_t& h, short8_t& l) {
    float v[8] = {a.x,a.y,a.z,a.w, b.x,b.y,b.z,b.w};
#pragma unroll
    for (int j = 0; j < 8; ++j) {
        u16 hh = f2bf(v[j]);
        h[j] = (short)hh; l[j] = (short)f2bf(v[j] - bf2f(hh));
    }
}
__device__ __forceinline__ short8_t cvt8(float4 a, float4 b) {
    float v[8] = {a.x,a.y,a.z,a.w, b.x,b.y,b.z,b.w};
    short8_t h;
#pragma unroll
    for (int j = 0; j < 8; ++j) h[j] = (short)f2bf(v[j]);
    return h;
}

// ---------------------------------------------------------------------------
// K0: emb/Wd -> bf16 hi/lo; cnorm (f64); zero rownorm/lossacc/flagcnt
// ---------------------------------------------------------------------------
__global__ void k_init(const float* __restrict__ emb, const float* __restrict__ Wd,
                       u16* __restrict__ embH, u16* __restrict__ embL,
                       u16* __restrict__ WdH,  u16* __restrict__ WdL,
                       float* __restrict__ cnorm, float* __restrict__ rownorm,
                       float* __restrict__ lossacc, int* __restrict__ flagcnt) {
    int tid = blockIdx.x * 256 + threadIdx.x;           // 65536 threads
    for (int i = tid; i < DE * DIN; i += 65536) {
        float v = Wd[i]; u16 h = f2bf(v);
        WdH[i] = h; WdL[i] = f2bf(v - bf2f(h));
    }
    for (int i = tid; i < NC * DE; i += 65536) {
        float v = emb[i]; u16 h = f2bf(v);
        embH[i] = h; embL[i] = f2bf(v - bf2f(h));
    }
    if (tid < M_) rownorm[tid] = 0.f;
    if (tid < NC) {
        const float* c = emb + (size_t)tid * DE;
        double s = 0.0;
        for (int j = 0; j < DE; ++j) { double v = c[j]; s += v * v; }
        cnorm[tid] = (float)s;
    }
    if (tid < 16) lossacc[tid] = 0.f;
    if (tid == 16) *flagcnt = 0;
}

// ---------------------------------------------------------------------------
// K1: z_e = Z @ Wd^T, 32x32x16 MFMA, 3-term hi/lo.
// grid 1024 = 512 z-tiles x 2 M-halves; 256 thr / 4 waves; 2 blocks/CU cap.
// Block owns 128 z-rows x 128 M-cols. Wave owns 32 z-rows, acc[4] f32x16
// (64 regs). Wd half-tile [128][32K] double-buffered in LDS (aH/aL[2]),
// 40-u16 padded rows (proven conflict-free pattern from k_argmin).
// T14 split: issue kt+1 global loads -> 24 MFMA on buf kt -> barrier ->
// ds_write buf kt+1 -> barrier. Peak regs ~175 unified -> no spill at the
// 256-reg/wave cap. rownorm: per-half partial via shfl + atomicAdd.
// ---------------------------------------------------------------------------
__global__ __launch_bounds__(256, 2) void k_ze(
        const float* __restrict__ Z,
        const u16* __restrict__ WdH, const u16* __restrict__ WdL,
        float* __restrict__ zeF, float* __restrict__ rownorm) {
    __shared__ __align__(16) u16 aH[2][128 * 40];
    __shared__ __align__(16) u16 aL[2][128 * 40];
    const int bz = blockIdx.x >> 1, mh = blockIdx.x & 1;
    const int m0 = bz * 128;              // z-row base
    const int nb = mh * 128;              // M-half (output col) base
    const int t = threadIdx.x, lane = t & 63, wv = t >> 6;
    const int lc = lane & 31, hi = lane >> 5;
    const int zrow = m0 + wv * 32 + lc;
    const int srow = t >> 1, sseg = (t & 1) * 16;   // staging: row, 16-u16 half
    const float* Zrow = Z + (size_t)zrow * DIN;

    uint4 qh[2], ql[2];
#define WD_LOAD(kt_) { \
        size_t off = (size_t)(nb + srow) * DIN + (size_t)(kt_) * 32 + sseg; \
        qh[0] = *(const uint4*)(WdH + off); qh[1] = *(const uint4*)(WdH + off + 8); \
        ql[0] = *(const uint4*)(WdL + off); ql[1] = *(const uint4*)(WdL + off + 8); }
#define WD_WRITE(b_) { \
        *(uint4*)&aH[b_][srow * 40 + sseg]     = qh[0]; \
        *(uint4*)&aH[b_][srow * 40 + sseg + 8] = qh[1]; \
        *(uint4*)&aL[b_][srow * 40 + sseg]     = ql[0]; \
        *(uint4*)&aL[b_][srow * 40 + sseg + 8] = ql[1]; }
#define Z_LOAD(kt_, d_) { \
        const float4* zp = (const float4*)(Zrow + (kt_) * 32 + hi * 8); \
        d_[0] = zp[0]; d_[1] = zp[1]; \
        const float4* zq = (const float4*)(Zrow + (kt_) * 32 + 16 + hi * 8); \
        d_[2] = zq[0]; d_[3] = zq[1]; }

    float4 zr[4], zn[4];
    Z_LOAD(0, zr);
    WD_LOAD(0);
    WD_WRITE(0);
    __syncthreads();

    f32x16_t acc[4];
#pragma unroll
    for (int s = 0; s < 4; ++s)
#pragma unroll
        for (int r = 0; r < 16; ++r) acc[s][r] = 0.f;

    for (int kt = 0; kt < 16; ++kt) {
        if (kt < 15) { WD_LOAD(kt + 1); Z_LOAD(kt + 1, zn); }
        short8_t zh0, zl0, zh1, zl1;
        cvt8_hl(zr[0], zr[1], zh0, zl0);
        cvt8_hl(zr[2], zr[3], zh1, zl1);
        const int buf = kt & 1;
#pragma unroll
        for (int ks = 0; ks < 2; ++ks) {
            short8_t zbh = ks ? zh1 : zh0, zbl = ks ? zl1 : zl0;
#pragma unroll
            for (int s = 0; s < 4; ++s) {
                const int lo = (s * 32 + lc) * 40 + ks * 16 + hi * 8;
                short8_t ah = *(const short8_t*)&aH[buf][lo];
                short8_t al = *(const short8_t*)&aL[buf][lo];
                acc[s] = __builtin_amdgcn_mfma_f32_32x32x16_bf16(ah, zbh, acc[s], 0, 0, 0);
                acc[s] = __builtin_amdgcn_mfma_f32_32x32x16_bf16(ah, zbl, acc[s], 0, 0, 0);
                acc[s] = __builtin_amdgcn_mfma_f32_32x32x16_bf16(al, zbh, acc[s], 0, 0, 0);
            }
        }
        if (kt < 15) {
            __syncthreads();
            WD_WRITE((kt + 1) & 1);
            zr[0] = zn[0]; zr[1] = zn[1]; zr[2] = zn[2]; zr[3] = zn[3];
            __syncthreads();
        }
    }
#undef WD_LOAD
#undef WD_WRITE
#undef Z_LOAD

    // epilogue: acc[s][r] -> e = nb + s*32 + (r&3)+8*(r>>2)+4*hi, col = zrow.
    // lane pair (lc, lc+32) holds complementary e-sets of the same zrow.
    float rn = 0.f;
#pragma unroll
    for (int s = 0; s < 4; ++s)
#pragma unroll
        for (int r = 0; r < 16; ++r) rn += acc[s][r] * acc[s][r];
    rn += __shfl_xor(rn, 32, 64);
    if (lane < 32) atomicAdd(&rownorm[zrow], rn);
#pragma unroll
    for (int s = 0; s < 4; ++s)
#pragma unroll
        for (int q = 0; q < 4; ++q) {
            float4 v = {acc[s][q * 4 + 0], acc[s][q * 4 + 1],
                        acc[s][q * 4 + 2], acc[s][q * 4 + 3]};
            *(float4*)(zeF + (size_t)zrow * DE + nb + s * 32 + q * 8 + hi * 4) = v;
        }
}

// ---------------------------------------------------------------------------
// K2: argmin, 32x32x16 MFMA (3-term hi/lo). grid 512 x 256 thr (4 waves).
// (round-1 proven version, unchanged)
// ---------------------------------------------------------------------------
__global__ __launch_bounds__(256, 2) void k_argmin(
        const float* __restrict__ zeF,
        const u16* __restrict__ embH, const u16* __restrict__ embL,
        const float* __restrict__ cnorm, const float* __restrict__ rownorm,
        u16* __restrict__ codew, int* __restrict__ flaglist,
        int* __restrict__ flagcnt, float* __restrict__ lossacc) {
    __shared__ __align__(16) u16 aH[2][128 * 40];
    __shared__ __align__(16) u16 aL[2][128 * 40];
    __shared__ float lCn[NC];
    __shared__ float lLoss[128];
    const int m0 = blockIdx.x * 128;
    const int t = threadIdx.x, lane = t & 63, wv = t >> 6;
    const int lc = lane & 31, hi = lane >> 5;
    const int zrow = m0 + wv * 32 + lc;

    for (int i = t; i < NC; i += 256) lCn[i] = cnorm[i];

    // B-regs: this lane's z row, all K=256 in 16 chunks of 16, hi/lo
    short8_t bh[16], bl[16];
#pragma unroll
    for (int c = 0; c < 16; ++c) {
        const float4* zp = (const float4*)(zeF + (size_t)zrow * DE + c * 16 + hi * 8);
        cvt8_hl(zp[0], zp[1], bh[c], bl[c]);
    }

#define STAGE_E(ct_, kt_, b_) { \
        _Pragma("unroll") \
        for (int j = 0; j < 2; ++j) { \
            int idx = t + j * 256; \
            int row = idx >> 2, seg = (idx & 3) * 8; \
            size_t off = (size_t)((ct_) * 128 + row) * DE + (kt_) * 32 + seg; \
            uint4 vh = *(const uint4*)(embH + off); \
            uint4 vl = *(const uint4*)(embL + off); \
            *(uint4*)&aH[b_][row * 40 + seg] = vh; \
            *(uint4*)&aL[b_][row * 40 + seg] = vl; \
        } }

    float best = 3.4e38f, sec = 3.4e38f; int bidx = 0;
    STAGE_E(0, 0, 0);
    for (int ct = 0; ct < 8; ++ct) {
        f32x16_t acc[4];
#pragma unroll
        for (int s = 0; s < 4; ++s)
#pragma unroll
            for (int r = 0; r < 16; ++r) acc[s][r] = 0.f;
#pragma unroll
        for (int kt = 0; kt < 8; ++kt) {
            __syncthreads();
            if (kt < 7)      STAGE_E(ct, kt + 1, (kt + 1) & 1)
            else if (ct < 7) STAGE_E(ct + 1, 0, 0)
            const int buf = kt & 1;
#pragma unroll
            for (int ks = 0; ks < 2; ++ks) {
                const int c = kt * 2 + ks;
#pragma unroll
                for (int s = 0; s < 4; ++s) {
                    short8_t ah = *(const short8_t*)&aH[buf][(s * 32 + lc) * 40 + ks * 16 + hi * 8];
                    short8_t al = *(const short8_t*)&aL[buf][(s * 32 + lc) * 40 + ks * 16 + hi * 8];
                    acc[s] = __builtin_amdgcn_mfma_f32_32x32x16_bf16(ah, bh[c], acc[s], 0, 0, 0);
                    acc[s] = __builtin_amdgcn_mfma_f32_32x32x16_bf16(ah, bl[c], acc[s], 0, 0, 0);
                    acc[s] = __builtin_amdgcn_mfma_f32_32x32x16_bf16(al, bh[c], acc[s], 0, 0, 0);
                }
            }
        }
        // fold chunk into best/sec
#pragma unroll
        for (int s = 0; s < 4; ++s)
#pragma unroll
            for (int r = 0; r < 16; ++r) {
                const int cidx = ct * 128 + s * 32 + (r & 3) + 8 * (r >> 2) + 4 * hi;
                float d = fmaf(-2.f, acc[s][r], lCn[cidx]);
                bool lt = d < best;
                sec  = lt ? best : fminf(sec, d);
                best = lt ? d : best;
                bidx = lt ? cidx : bidx;
            }
    }
#undef STAGE_E
    // merge lane pair (l, l^32): both halves of the same z-column
    {
        float ob = __shfl_xor(best, 32, 64);
        float os = __shfl_xor(sec,  32, 64);
        int   oi = __shfl_xor(bidx, 32, 64);
        float ns = fminf(fminf(sec, os), fmaxf(best, ob));
        if (ob < best) { best = ob; bidx = oi; }
        sec = ns;
    }
    if (lane < 32) {
        codew[zrow] = (u16)bidx;
        if (sec - best < 0.02f) {
            int pos = atomicAdd(flagcnt, 1);
            if (pos < FLAGCAP) flaglist[pos] = zrow;
        }
        lLoss[wv * 32 + lc] = rownorm[zrow] + best;
    }
    __syncthreads();
    for (int str = 64; str > 0; str >>= 1) {
        if (t < str) lLoss[t] += lLoss[t + str];
        __syncthreads();
    }
    if (t == 0) atomicAdd(&lossacc[m0 >> 12], lLoss[0]);
}

// ---------------------------------------------------------------------------
// K2b: f64 exact re-argmin for flagged rows, from pristine f32 inputs.
// ---------------------------------------------------------------------------
__global__ __launch_bounds__(256) void k_refine(
        const float* __restrict__ Z, const float* __restrict__ Wd,
        const float* __restrict__ emb,
        const int* __restrict__ flaglist, const int* __restrict__ flagcnt,
        u16* __restrict__ codew) {
    __shared__ float  lz[DIN];
    __shared__ double lze[DE];
    __shared__ double ld[256];
    __shared__ int    li[256];
    int n = *flagcnt; if (n < 0) n = 0; if (n > FLAGCAP) n = FLAGCAP;
    int t = threadIdx.x;
    for (int f = blockIdx.x; f < n; f += gridDim.x) {
        int row = flaglist[f] & (M_ - 1);
        __syncthreads();
        for (int i = t; i < DIN; i += 256) lz[i] = Z[(size_t)row * DIN + i];
        __syncthreads();
        double a = 0.0;
        const float* wr = Wd + (size_t)t * DIN;
        for (int k = 0; k < DIN; ++k) a += (double)lz[k] * (double)wr[k];
        lze[t] = a;
        __syncthreads();
        double bd = 1e300; int bi = 0;
        for (int cc = 0; cc < 4; ++cc) {
            int c = cc * 256 + t;
            const float* cr = emb + (size_t)c * DE;
            double s = 0.0;
            for (int e = 0; e < DE; ++e) {
                double diff = lze[e] - (double)cr[e];
                s += diff * diff;
            }
            if (s < bd) { bd = s; bi = c; }
        }
        ld[t] = bd; li[t] = bi;
        __syncthreads();
        for (int str = 128; str > 0; str >>= 1) {
            if (t < str) {
                double od = ld[t + str]; int oi = li[t + str];
                if (od < ld[t] || (od == ld[t] && oi < li[t])) { ld[t] = od; li[t] = oi; }
            }
            __syncthreads();
        }
        if (t == 0) codew[row] = (u16)li[0];
        __syncthreads();
    }
}

// ---------------------------------------------------------------------------
__global__ void k_loss(const float* __restrict__ lossacc,
                       float* __restrict__ out_commit, float* __restrict__ out_codebook) {
    int tid = threadIdx.x;
    if (tid < 16) {
        float v = lossacc[tid] * (1.f / 1048576.f);
        out_commit[tid] = v; out_codebook[tid] = v;
    }
}
__global__ void k_codef(const u16* __restrict__ codew, float* __restrict__ out_code) {
    int tid = blockIdx.x * 256 + threadIdx.x;
    if (tid < M_) out_code[tid] = (float)(codew[tid] & (NC - 1));
}

// ---------------------------------------------------------------------------
// K3: z_q_out = emb[code] @ Wu^T, single bf16 term.
// ---------------------------------------------------------------------------
__global__ __launch_bounds__(512) void k_gemm3(
        const float* __restrict__ emb, const float* __restrict__ Wu,
        const float* __restrict__ out_code, float* __restrict__ out) {
    __shared__ __align__(16) u16 gA[128 * 264];   // 67.6 KB
    const int bz = blockIdx.x >> 1, nh = blockIdx.x & 1;
    const int m0 = bz * 128;
    const int t = threadIdx.x, lane = t & 63, wv = t >> 6;
    const int lr = lane & 15, lg = lane >> 4;
    {
        const int row = t >> 2, seg = (t & 3) * 64;
        const int code = (int)out_code[m0 + row] & (NC - 1);
        const float* src = emb + (size_t)code * DE + seg;
#pragma unroll
        for (int j = 0; j < 8; ++j) {
            const float4* p = (const float4*)(src + j * 8);
            *(short8_t*)&gA[row * 264 + seg + j * 8] = cvt8(p[0], p[1]);
        }
    }
    __syncthreads();

    const int nbase = nh * 256 + wv * 32;
    f32x4_t acc[8][2];
#pragma unroll
    for (int i = 0; i < 8; ++i)
#pragma unroll
        for (int j = 0; j < 2; ++j) acc[i][j] = (f32x4_t){0.f, 0.f, 0.f, 0.f};

#pragma unroll
    for (int kt = 0; kt < 8; ++kt) {
        const int k0 = kt * 32 + lg * 8;
        short8_t b0, b1;
        {
            const float4* p = (const float4*)(Wu + (size_t)(nbase + lr) * DE + k0);
            b0 = cvt8(p[0], p[1]);
            const float4* q = (const float4*)(Wu + (size_t)(nbase + 16 + lr) * DE + k0);
            b1 = cvt8(q[0], q[1]);
        }
#pragma unroll
        for (int mi = 0; mi < 8; ++mi) {
            short8_t a = *(const short8_t*)&gA[(mi * 16 + lr) * 264 + k0];
            acc[mi][0] = __builtin_amdgcn_mfma_f32_16x16x32_bf16(a, b0, acc[mi][0], 0, 0, 0);
            acc[mi][1] = __builtin_amdgcn_mfma_f32_16x16x32_bf16(a, b1, acc[mi][1], 0, 0, 0);
        }
    }
#pragma unroll
    for (int mi = 0; mi < 8; ++mi)
#pragma unroll
        for (int reg = 0; reg < 4; ++reg) {
            const int zr = m0 + mi * 16 + lg * 4 + reg;
            out[(size_t)zr * DIN + nbase + lr]      = acc[mi][0][reg];
            out[(size_t)zr * DIN + nbase + 16 + lr] = acc[mi][1][reg];
        }
}

// ---------------------------------------------------------------------------
extern "C" void kernel_launch(void* const* d_in, const int* in_sizes, int n_in,
                              void* d_out, int out_size, void* d_ws, size_t ws_size,
                              hipStream_t stream) {
    const float* Z   = (const float*)d_in[0];   // [16,4096,512] f32
    const float* E   = (const float*)d_in[1];   // [1024,256]    f32
    const float* Wd  = (const float*)d_in[2];   // [256,512]     f32
    const float* Wu  = (const float*)d_in[3];   // [512,256]     f32

    float* out       = (float*)d_out;           // f32 outputs, concat
    float* out_zq    = out;                     // [0, 33554432)
    float* out_com   = out + 33554432;          // 16
    float* out_cb    = out + 33554448;          // 16
    float* out_code  = out + 33554464;          // 65536
    float* out_ze    = out + 33620000;          // 16,777,216

    char* scr = (char*)d_out;
    u16*   embH     = (u16*)  (scr + 0);          // 524,288 B
    u16*   embL     = (u16*)  (scr + 524288);     // 524,288 B
    u16*   WdH      = (u16*)  (scr + 1048576);    // 262,144 B
    u16*   WdL      = (u16*)  (scr + 1310720);    // 262,144 B
    float* cnorm    = (float*)(scr + 1572864);    //   4,096 B
    float* rownorm  = (float*)(scr + 1576960);    // 262,144 B
    u16*   codew    = (u16*)  (scr + 1839104);    // 131,072 B
    int*   flaglist = (int*)  (scr + 1970176);    //  65,536 B
    int*   flagcnt  = (int*)  (scr + 2035712);    //      64 B
    float* lossacc  = (float*)(scr + 2035776);    //      64 B
    (void)d_ws; (void)ws_size; (void)in_sizes; (void)n_in; (void)out_size;

    k_init  <<<256,  256, 0, stream>>>(E, Wd, embH, embL, WdH, WdL, cnorm,
                                       rownorm, lossacc, flagcnt);
    k_ze    <<<1024, 256, 0, stream>>>(Z, WdH, WdL, out_ze, rownorm);
    k_argmin<<<512,  256, 0, stream>>>(out_ze, embH, embL, cnorm, rownorm,
                                       codew, flaglist, flagcnt, lossacc);
    k_refine<<<128,  256, 0, stream>>>(Z, Wd, E, flaglist, flagcnt, codew);
    k_loss  <<<1,    64,  0, stream>>>(lossacc, out_com, out_cb);
    k_codef <<<256,  256, 0, stream>>>(codew, out_code);
    k_gemm3 <<<1024, 512, 0, stream>>>(E, Wu, out_code, out_zq);
}

// Round 5
// 362.451 us; speedup vs baseline: 1.2363x; 1.1412x over previous
//
#include <hip/hip_runtime.h>
#include <stdint.h>

#define DIN  512
#define DE   256
#define NC   1024
#define M_   65536
#define FLAGCAP 16384

typedef unsigned short u16;
typedef __attribute__((ext_vector_type(8))) short short8_t;   // 8 bf16
typedef __attribute__((ext_vector_type(4))) float f32x4_t;    // MFMA acc (16x16)
typedef __attribute__((ext_vector_type(16))) float f32x16_t;  // MFMA acc (32x32)

__device__ __forceinline__ float bf2f(u16 u) {
    unsigned x = ((unsigned)u) << 16; return __builtin_bit_cast(float, x);
}
__device__ __forceinline__ u16 f2bf(float f) {
    unsigned x = __builtin_bit_cast(unsigned, f);
    x += 0x7fffu + ((x >> 16) & 1u);
    return (u16)(x >> 16);
}
__device__ __forceinline__ void cvt8_hl(float4 a, float4 b, short8_t& h, short8_t& l) {
    float v[8] = {a.x,a.y,a.z,a.w, b.x,b.y,b.z,b.w};
#pragma unroll
    for (int j = 0; j < 8; ++j) {
        u16 hh = f2bf(v[j]);
        h[j] = (short)hh; l[j] = (short)f2bf(v[j] - bf2f(hh));
    }
}
__device__ __forceinline__ short8_t cvt8(float4 a, float4 b) {
    float v[8] = {a.x,a.y,a.z,a.w, b.x,b.y,b.z,b.w};
    short8_t h;
#pragma unroll
    for (int j = 0; j < 8; ++j) h[j] = (short)f2bf(v[j]);
    return h;
}

// ---------------------------------------------------------------------------
// K0: emb/Wd -> bf16 hi/lo; cnorm (f64); zero lossacc/flagcnt
// ---------------------------------------------------------------------------
__global__ void k_init(const float* __restrict__ emb, const float* __restrict__ Wd,
                       u16* __restrict__ embH, u16* __restrict__ embL,
                       u16* __restrict__ WdH,  u16* __restrict__ WdL,
                       float* __restrict__ cnorm,
                       float* __restrict__ lossacc, int* __restrict__ flagcnt) {
    int tid = blockIdx.x * 256 + threadIdx.x;           // 65536 threads
    for (int i = tid; i < DE * DIN; i += 65536) {
        float v = Wd[i]; u16 h = f2bf(v);
        WdH[i] = h; WdL[i] = f2bf(v - bf2f(h));
    }
    for (int i = tid; i < NC * DE; i += 65536) {
        float v = emb[i]; u16 h = f2bf(v);
        embH[i] = h; embL[i] = f2bf(v - bf2f(h));
    }
    if (tid < NC) {
        const float* c = emb + (size_t)tid * DE;
        double s = 0.0;
        for (int j = 0; j < DE; ++j) { double v = c[j]; s += v * v; }
        cnorm[tid] = (float)s;
    }
    if (tid < 16) lossacc[tid] = 0.f;
    if (tid == 16) *flagcnt = 0;
}

// ---------------------------------------------------------------------------
// K1: z_e = Z @ Wd^T, 32x32x16 MFMA, 3-term hi/lo.  OPERANDS SWAPPED vs r4:
// A = z-tile (LDS, [128][40] hi/lo, double-buffered), B = Wd rows per-lane
// in registers (prefetched one kt ahead; Wd is L2-resident).
// D: row = z-row (via (r&3)+8*(r>>2)+4*hi), col = lane&31 = M-index
// -> epilogue stores are 128 B contiguous per z-row (coalesced, no partial
// sectors). grid 1024 = 512 z-tiles x 2 M-halves; 256 thr / 4 waves.
// Wave: 128 z-rows x 32 M cols, acc[4] f32x16 (64 regs). No rownorm here
// (computed in k_argmin for free).
// ---------------------------------------------------------------------------
__global__ __launch_bounds__(256, 2) void k_ze(
        const float* __restrict__ Z,
        const u16* __restrict__ WdH, const u16* __restrict__ WdL,
        float* __restrict__ zeF) {
    __shared__ __align__(16) u16 aH[2][128 * 40];
    __shared__ __align__(16) u16 aL[2][128 * 40];
    const int bz = blockIdx.x >> 1, mh = blockIdx.x & 1;
    const int m0 = bz * 128;              // z-row base
    const int nb = mh * 128;              // M-half (output col) base
    const int t = threadIdx.x, lane = t & 63, wv = t >> 6;
    const int lc = lane & 31, hi = lane >> 5;
    const int zsr = t >> 1, zss = (t & 1) * 16;   // staging: z-row, 16-f seg
    const int wdrow = nb + wv * 32 + lc;          // this lane's Wd (M) row
    const u16* WdHr = WdH + (size_t)wdrow * DIN;
    const u16* WdLr = WdL + (size_t)wdrow * DIN;

    float4 zf[4];
#define Z_LD(kt_) { \
        const float4* p = (const float4*)(Z + (size_t)(m0 + zsr) * DIN + (kt_) * 32 + zss); \
        zf[0] = p[0]; zf[1] = p[1]; zf[2] = p[2]; zf[3] = p[3]; }
#define Z_WR(b_) { \
        short8_t h0, l0, h1, l1; \
        cvt8_hl(zf[0], zf[1], h0, l0); cvt8_hl(zf[2], zf[3], h1, l1); \
        *(short8_t*)&aH[b_][zsr * 40 + zss]     = h0; \
        *(short8_t*)&aH[b_][zsr * 40 + zss + 8] = h1; \
        *(short8_t*)&aL[b_][zsr * 40 + zss]     = l0; \
        *(short8_t*)&aL[b_][zsr * 40 + zss + 8] = l1; }
#define WD_LD(kt_, H_, L_) { \
        H_[0] = *(const short8_t*)(WdHr + (kt_) * 32 + hi * 8); \
        H_[1] = *(const short8_t*)(WdHr + (kt_) * 32 + 16 + hi * 8); \
        L_[0] = *(const short8_t*)(WdLr + (kt_) * 32 + hi * 8); \
        L_[1] = *(const short8_t*)(WdLr + (kt_) * 32 + 16 + hi * 8); }

    short8_t wh[2], wl[2], nwh[2], nwl[2];
    Z_LD(0);
    WD_LD(0, wh, wl);
    Z_WR(0);
    __syncthreads();

    f32x16_t acc[4];
#pragma unroll
    for (int s = 0; s < 4; ++s)
#pragma unroll
        for (int r = 0; r < 16; ++r) acc[s][r] = 0.f;

    for (int kt = 0; kt < 16; ++kt) {
        if (kt < 15) { Z_LD(kt + 1); WD_LD(kt + 1, nwh, nwl); }
        const int buf = kt & 1;
#pragma unroll
        for (int ks = 0; ks < 2; ++ks) {
#pragma unroll
            for (int s = 0; s < 4; ++s) {
                const int lo = (s * 32 + lc) * 40 + ks * 16 + hi * 8;
                short8_t zh = *(const short8_t*)&aH[buf][lo];
                short8_t zl = *(const short8_t*)&aL[buf][lo];
                acc[s] = __builtin_amdgcn_mfma_f32_32x32x16_bf16(zh, wh[ks], acc[s], 0, 0, 0);
                acc[s] = __builtin_amdgcn_mfma_f32_32x32x16_bf16(zh, wl[ks], acc[s], 0, 0, 0);
                acc[s] = __builtin_amdgcn_mfma_f32_32x32x16_bf16(zl, wh[ks], acc[s], 0, 0, 0);
            }
        }
        if (kt < 15) {
            __syncthreads();
            Z_WR((kt + 1) & 1);
            wh[0] = nwh[0]; wh[1] = nwh[1];
            wl[0] = nwl[0]; wl[1] = nwl[1];
            __syncthreads();
        }
    }
#undef Z_LD
#undef Z_WR
#undef WD_LD

    // epilogue: acc[s][r] -> zeF[m0 + s*32 + (r&3)+8*(r>>2)+4*hi][nb+wv*32+lc]
    // lanes 0..31 contiguous -> 128 B per z-row per instruction.
#pragma unroll
    for (int s = 0; s < 4; ++s)
#pragma unroll
        for (int r = 0; r < 16; ++r) {
            const int zr = m0 + s * 32 + (r & 3) + 8 * (r >> 2) + 4 * hi;
            zeF[(size_t)zr * DE + nb + wv * 32 + lc] = acc[s][r];
        }
}

// ---------------------------------------------------------------------------
// K2: argmin, 32x32x16 MFMA (3-term hi/lo). grid 512 x 256 thr (4 waves).
// rownorm computed in-register during the B-load (lane covers half the row;
// shfl_xor(32) completes it).
// ---------------------------------------------------------------------------
__global__ __launch_bounds__(256, 2) void k_argmin(
        const float* __restrict__ zeF,
        const u16* __restrict__ embH, const u16* __restrict__ embL,
        const float* __restrict__ cnorm,
        u16* __restrict__ codew, int* __restrict__ flaglist,
        int* __restrict__ flagcnt, float* __restrict__ lossacc) {
    __shared__ __align__(16) u16 aH[2][128 * 40];
    __shared__ __align__(16) u16 aL[2][128 * 40];
    __shared__ float lCn[NC];
    __shared__ float lLoss[128];
    const int m0 = blockIdx.x * 128;
    const int t = threadIdx.x, lane = t & 63, wv = t >> 6;
    const int lc = lane & 31, hi = lane >> 5;
    const int zrow = m0 + wv * 32 + lc;

    for (int i = t; i < NC; i += 256) lCn[i] = cnorm[i];

    // B-regs: this lane's z row, all K=256 in 16 chunks of 16, hi/lo.
    // rownorm accumulated on the fly.
    short8_t bh[16], bl[16];
    float rn = 0.f;
#pragma unroll
    for (int c = 0; c < 16; ++c) {
        const float4* zp = (const float4*)(zeF + (size_t)zrow * DE + c * 16 + hi * 8);
        float4 a = zp[0], b = zp[1];
        rn += a.x*a.x + a.y*a.y + a.z*a.z + a.w*a.w
            + b.x*b.x + b.y*b.y + b.z*b.z + b.w*b.w;
        cvt8_hl(a, b, bh[c], bl[c]);
    }
    rn += __shfl_xor(rn, 32, 64);

#define STAGE_E(ct_, kt_, b_) { \
        _Pragma("unroll") \
        for (int j = 0; j < 2; ++j) { \
            int idx = t + j * 256; \
            int row = idx >> 2, seg = (idx & 3) * 8; \
            size_t off = (size_t)((ct_) * 128 + row) * DE + (kt_) * 32 + seg; \
            uint4 vh = *(const uint4*)(embH + off); \
            uint4 vl = *(const uint4*)(embL + off); \
            *(uint4*)&aH[b_][row * 40 + seg] = vh; \
            *(uint4*)&aL[b_][row * 40 + seg] = vl; \
        } }

    float best = 3.4e38f, sec = 3.4e38f; int bidx = 0;
    STAGE_E(0, 0, 0);
    for (int ct = 0; ct < 8; ++ct) {
        f32x16_t acc[4];
#pragma unroll
        for (int s = 0; s < 4; ++s)
#pragma unroll
            for (int r = 0; r < 16; ++r) acc[s][r] = 0.f;
#pragma unroll
        for (int kt = 0; kt < 8; ++kt) {
            __syncthreads();
            if (kt < 7)      STAGE_E(ct, kt + 1, (kt + 1) & 1)
            else if (ct < 7) STAGE_E(ct + 1, 0, 0)
            const int buf = kt & 1;
#pragma unroll
            for (int ks = 0; ks < 2; ++ks) {
                const int c = kt * 2 + ks;
#pragma unroll
                for (int s = 0; s < 4; ++s) {
                    short8_t ah = *(const short8_t*)&aH[buf][(s * 32 + lc) * 40 + ks * 16 + hi * 8];
                    short8_t al = *(const short8_t*)&aL[buf][(s * 32 + lc) * 40 + ks * 16 + hi * 8];
                    acc[s] = __builtin_amdgcn_mfma_f32_32x32x16_bf16(ah, bh[c], acc[s], 0, 0, 0);
                    acc[s] = __builtin_amdgcn_mfma_f32_32x32x16_bf16(ah, bl[c], acc[s], 0, 0, 0);
                    acc[s] = __builtin_amdgcn_mfma_f32_32x32x16_bf16(al, bh[c], acc[s], 0, 0, 0);
                }
            }
        }
        // fold chunk into best/sec
#pragma unroll
        for (int s = 0; s < 4; ++s)
#pragma unroll
            for (int r = 0; r < 16; ++r) {
                const int cidx = ct * 128 + s * 32 + (r & 3) + 8 * (r >> 2) + 4 * hi;
                float d = fmaf(-2.f, acc[s][r], lCn[cidx]);
                bool lt = d < best;
                sec  = lt ? best : fminf(sec, d);
                best = lt ? d : best;
                bidx = lt ? cidx : bidx;
            }
    }
#undef STAGE_E
    // merge lane pair (l, l^32): both halves of the same z-column
    {
        float ob = __shfl_xor(best, 32, 64);
        float os = __shfl_xor(sec,  32, 64);
        int   oi = __shfl_xor(bidx, 32, 64);
        float ns = fminf(fminf(sec, os), fmaxf(best, ob));
        if (ob < best) { best = ob; bidx = oi; }
        sec = ns;
    }
    if (lane < 32) {
        codew[zrow] = (u16)bidx;
        if (sec - best < 0.02f) {
            int pos = atomicAdd(flagcnt, 1);
            if (pos < FLAGCAP) flaglist[pos] = zrow;
        }
        lLoss[wv * 32 + lc] = rn + best;
    }
    __syncthreads();
    for (int str = 64; str > 0; str >>= 1) {
        if (t < str) lLoss[t] += lLoss[t + str];
        __syncthreads();
    }
    if (t == 0) atomicAdd(&lossacc[m0 >> 12], lLoss[0]);
}

// ---------------------------------------------------------------------------
// K2b: f64 exact re-argmin for flagged rows, from pristine f32 inputs.
// ---------------------------------------------------------------------------
__global__ __launch_bounds__(256) void k_refine(
        const float* __restrict__ Z, const float* __restrict__ Wd,
        const float* __restrict__ emb,
        const int* __restrict__ flaglist, const int* __restrict__ flagcnt,
        u16* __restrict__ codew) {
    __shared__ float  lz[DIN];
    __shared__ double lze[DE];
    __shared__ double ld[256];
    __shared__ int    li[256];
    int n = *flagcnt; if (n < 0) n = 0; if (n > FLAGCAP) n = FLAGCAP;
    int t = threadIdx.x;
    for (int f = blockIdx.x; f < n; f += gridDim.x) {
        int row = flaglist[f] & (M_ - 1);
        __syncthreads();
        for (int i = t; i < DIN; i += 256) lz[i] = Z[(size_t)row * DIN + i];
        __syncthreads();
        double a = 0.0;
        const float* wr = Wd + (size_t)t * DIN;
        for (int k = 0; k < DIN; ++k) a += (double)lz[k] * (double)wr[k];
        lze[t] = a;
        __syncthreads();
        double bd = 1e300; int bi = 0;
        for (int cc = 0; cc < 4; ++cc) {
            int c = cc * 256 + t;
            const float* cr = emb + (size_t)c * DE;
            double s = 0.0;
            for (int e = 0; e < DE; ++e) {
                double diff = lze[e] - (double)cr[e];
                s += diff * diff;
            }
            if (s < bd) { bd = s; bi = c; }
        }
        ld[t] = bd; li[t] = bi;
        __syncthreads();
        for (int str = 128; str > 0; str >>= 1) {
            if (t < str) {
                double od = ld[t + str]; int oi = li[t + str];
                if (od < ld[t] || (od == ld[t] && oi < li[t])) { ld[t] = od; li[t] = oi; }
            }
            __syncthreads();
        }
        if (t == 0) codew[row] = (u16)li[0];
        __syncthreads();
    }
}

// ---------------------------------------------------------------------------
__global__ void k_loss(const float* __restrict__ lossacc,
                       float* __restrict__ out_commit, float* __restrict__ out_codebook) {
    int tid = threadIdx.x;
    if (tid < 16) {
        float v = lossacc[tid] * (1.f / 1048576.f);
        out_commit[tid] = v; out_codebook[tid] = v;
    }
}
__global__ void k_codef(const u16* __restrict__ codew, float* __restrict__ out_code) {
    int tid = blockIdx.x * 256 + threadIdx.x;
    if (tid < M_) out_code[tid] = (float)(codew[tid] & (NC - 1));
}

// ---------------------------------------------------------------------------
// K3: z_q_out = emb[code] @ Wu^T, single bf16 term.
// ---------------------------------------------------------------------------
__global__ __launch_bounds__(512) void k_gemm3(
        const float* __restrict__ emb, const float* __restrict__ Wu,
        const float* __restrict__ out_code, float* __restrict__ out) {
    __shared__ __align__(16) u16 gA[128 * 264];   // 67.6 KB
    const int bz = blockIdx.x >> 1, nh = blockIdx.x & 1;
    const int m0 = bz * 128;
    const int t = threadIdx.x, lane = t & 63, wv = t >> 6;
    const int lr = lane & 15, lg = lane >> 4;
    {
        const int row = t >> 2, seg = (t & 3) * 64;
        const int code = (int)out_code[m0 + row] & (NC - 1);
        const float* src = emb + (size_t)code * DE + seg;
#pragma unroll
        for (int j = 0; j < 8; ++j) {
            const float4* p = (const float4*)(src + j * 8);
            *(short8_t*)&gA[row * 264 + seg + j * 8] = cvt8(p[0], p[1]);
        }
    }
    __syncthreads();

    const int nbase = nh * 256 + wv * 32;
    f32x4_t acc[8][2];
#pragma unroll
    for (int i = 0; i < 8; ++i)
#pragma unroll
        for (int j = 0; j < 2; ++j) acc[i][j] = (f32x4_t){0.f, 0.f, 0.f, 0.f};

#pragma unroll
    for (int kt = 0; kt < 8; ++kt) {
        const int k0 = kt * 32 + lg * 8;
        short8_t b0, b1;
        {
            const float4* p = (const float4*)(Wu + (size_t)(nbase + lr) * DE + k0);
            b0 = cvt8(p[0], p[1]);
            const float4* q = (const float4*)(Wu + (size_t)(nbase + 16 + lr) * DE + k0);
            b1 = cvt8(q[0], q[1]);
        }
#pragma unroll
        for (int mi = 0; mi < 8; ++mi) {
            short8_t a = *(const short8_t*)&gA[(mi * 16 + lr) * 264 + k0];
            acc[mi][0] = __builtin_amdgcn_mfma_f32_16x16x32_bf16(a, b0, acc[mi][0], 0, 0, 0);
            acc[mi][1] = __builtin_amdgcn_mfma_f32_16x16x32_bf16(a, b1, acc[mi][1], 0, 0, 0);
        }
    }
#pragma unroll
    for (int mi = 0; mi < 8; ++mi)
#pragma unroll
        for (int reg = 0; reg < 4; ++reg) {
            const int zr = m0 + mi * 16 + lg * 4 + reg;
            out[(size_t)zr * DIN + nbase + lr]      = acc[mi][0][reg];
            out[(size_t)zr * DIN + nbase + 16 + lr] = acc[mi][1][reg];
        }
}

// ---------------------------------------------------------------------------
extern "C" void kernel_launch(void* const* d_in, const int* in_sizes, int n_in,
                              void* d_out, int out_size, void* d_ws, size_t ws_size,
                              hipStream_t stream) {
    const float* Z   = (const float*)d_in[0];   // [16,4096,512] f32
    const float* E   = (const float*)d_in[1];   // [1024,256]    f32
    const float* Wd  = (const float*)d_in[2];   // [256,512]     f32
    const float* Wu  = (const float*)d_in[3];   // [512,256]     f32

    float* out       = (float*)d_out;           // f32 outputs, concat
    float* out_zq    = out;                     // [0, 33554432)
    float* out_com   = out + 33554432;          // 16
    float* out_cb    = out + 33554448;          // 16
    float* out_code  = out + 33554464;          // 65536
    float* out_ze    = out + 33620000;          // 16,777,216

    char* scr = (char*)d_out;
    u16*   embH     = (u16*)  (scr + 0);          // 524,288 B
    u16*   embL     = (u16*)  (scr + 524288);     // 524,288 B
    u16*   WdH      = (u16*)  (scr + 1048576);    // 262,144 B
    u16*   WdL      = (u16*)  (scr + 1310720);    // 262,144 B
    float* cnorm    = (float*)(scr + 1572864);    //   4,096 B
    u16*   codew    = (u16*)  (scr + 1839104);    // 131,072 B
    int*   flaglist = (int*)  (scr + 1970176);    //  65,536 B
    int*   flagcnt  = (int*)  (scr + 2035712);    //      64 B
    float* lossacc  = (float*)(scr + 2035776);    //      64 B
    (void)d_ws; (void)ws_size; (void)in_sizes; (void)n_in; (void)out_size;

    k_init  <<<256,  256, 0, stream>>>(E, Wd, embH, embL, WdH, WdL, cnorm,
                                       lossacc, flagcnt);
    k_ze    <<<1024, 256, 0, stream>>>(Z, WdH, WdL, out_ze);
    k_argmin<<<512,  256, 0, stream>>>(out_ze, embH, embL, cnorm,
                                       codew, flaglist, flagcnt, lossacc);
    k_refine<<<128,  256, 0, stream>>>(Z, Wd, E, flaglist, flagcnt, codew);
    k_loss  <<<1,    64,  0, stream>>>(lossacc, out_com, out_cb);
    k_codef <<<256,  256, 0, stream>>>(codew, out_code);
    k_gemm3 <<<1024, 512, 0, stream>>>(E, Wu, out_code, out_zq);
}